// Round 10
// baseline (32.973 us; speedup 1.0000x reference)
//
#include <hip/hip_runtime.h>
#include <math.h>

#define CC 30
#define NBATCH 4096
#define NIJ 49
#define NPAIR 1225            // 49 ij * 25 tail channels (c = 5..29)
#define PSTR 7352             // per-wg partial stride in floats (6*NPAIR=7350, padded to /4)
#define F4TOT (PSTR / 4)      // 1838
#define THREADS 1024
#define SLABF4 1470           // float4 count of a 4-batch slab of one tensor

// ws layout (NO initialization required — every read location is written first):
//   offset 0     : scal[nwg][4]      (written by yolo_main)
//   offset 8192  : tbl[PSTR]         (written by yolo_reduce)
//   offset 40960 : parts[nwg][PSTR]  (written by yolo_main)

__global__ __launch_bounds__(THREADS)
void yolo_main(const float* __restrict__ y, const float* __restrict__ yh,
               float* __restrict__ scal, float* __restrict__ parts, int nwg)
{
    __shared__ __align__(16) float tY[4 * 1470];   // 23.5 KB
    __shared__ __align__(16) float tH[4 * 1470];   // 23.5 KB
    __shared__ float scr[4][16];

    const int tid = threadIdx.x;
    const int wg  = blockIdx.x;
    const int bpw = NBATCH / nwg;        // 16 for nwg=256
    const int nslab = bpw >> 2;          // 4

    // staging indices: 1470 float4 per tensor, 1024 threads -> 2 rounds (2nd masked)
    const int i0 = tid;
    const int i1r = tid + 1024;
    const int i1  = (i1r < SLABF4) ? i1r : (SLABF4 - 1);
    const bool w1 = (i1r < SLABF4);

    // slot ownership: 2 rounds; round 0 all tids < 1225 (all of 0..1023), round 1 tids < 201
    int  ijv[2], cv[2], pr[2];
    bool val[2];
    #pragma unroll
    for (int i = 0; i < 2; i++) {
        int p = tid + i * THREADS;
        val[i] = (p < NPAIR);
        pr[i]  = p;
        int pp = val[i] ? p : 0;
        ijv[i] = pp / 25;
        cv[i]  = 5 + pp % 25;
    }

    float D0[2] = {0,0}, B0[2] = {0,0}, C0[2] = {0,0};
    float D1[2] = {0,0}, B1[2] = {0,0}, C1[2] = {0,0};
    float obj = 0.f, noobj = 0.f, coord = 0.f, tt = 0.f;

    const float4* Yg = (const float4*)y;
    const float4* Hg = (const float4*)yh;
    float4* tY4 = (float4*)tY;
    float4* tH4 = (float4*)tH;

    // prologue: stage slab 0
    {
        const size_t f4 = (size_t)((wg * bpw) >> 2) * SLABF4;
        float4 a0 = Yg[f4+i0], a1 = Yg[f4+i1];
        float4 b0 = Hg[f4+i0], b1 = Hg[f4+i1];
        tY4[i0] = a0; if (w1) tY4[i1] = a1;
        tH4[i0] = b0; if (w1) tH4[i1] = b1;
    }
    __syncthreads();

    float4 ry0, ry1, rh0, rh1;

    for (int s = 0; s < nslab; s++) {
        if (s + 1 < nslab) {     // register prefetch of next slab (T14)
            const size_t nf4 = (size_t)((wg * bpw + (s+1)*4) >> 2) * SLABF4;
            ry0 = Yg[nf4+i0]; ry1 = Yg[nf4+i1];
            rh0 = Hg[nf4+i0]; rh1 = Hg[nf4+i1];
        }

        // ---- pointwise: 196 cells in this slab ----
        if (tid < 4 * NIJ) {
            const int base = tid * CC;
            float y0 = tY[base],     h0 = tH[base];
            float y5 = tY[base + 5], h5 = tH[base + 5];
            float d0 = y0 - h0; d0 *= d0;
            float d5 = y5 - h5; d5 *= d5;
            const bool m0 = (y0 == 1.0f), m1 = (y5 == 1.0f);
            obj   += (m0 ? d0 : 0.f) + (m1 ? d5 : 0.f);
            noobj += (m0 ? 0.f : d0) + (m1 ? 0.f : d5);
            if (m0) {
                float a  = tY[base + 1] - tH[base + 1];
                float b2 = tY[base + 2] - tH[base + 2];
                float c1 = sqrtf(tY[base + 3]) - sqrtf(tH[base + 3]);
                float c2 = sqrtf(tY[base + 4]) - sqrtf(tH[base + 4]);
                coord += a * a + b2 * b2 + c1 * c1 + c2 * c2;
            }
            if (m1) {
                float a  = tY[base + 6] - tH[base + 6];
                float b2 = tY[base + 7] - tH[base + 7];
                float c1 = sqrtf(tY[base + 8]) - sqrtf(tH[base + 8]);
                float c2 = sqrtf(tY[base + 9]) - sqrtf(tH[base + 9]);
                coord += a * a + b2 * b2 + c1 * c1 + c2 * c2;
            }
        }

        // ---- slot phase: register accumulation, no atomics ----
        #pragma unroll
        for (int b = 0; b < 4; b++) {
            #pragma unroll
            for (int i = 0; i < 2; i++) {
                if (!val[i]) continue;
                const int cb = b * 1470 + ijv[i] * CC;
                const float w0 = (tY[cb] == 1.0f) ? 1.f : 0.f;
                const float wk = (cv[i] >= 10 && tY[cb + 5] == 1.0f) ? 1.f : 0.f;
                const float t  = tY[cb + cv[i]];
                const float th = tH[cb + cv[i]];
                const float e  = __expf(th);
                const float te = t * e, ee = e * e, t2 = t * t;
                D0[i] = fmaf(e,  w0, D0[i]);
                B0[i] = fmaf(te, w0, B0[i]);
                C0[i] = fmaf(ee, w0, C0[i]);
                D1[i] = fmaf(e,  wk, D1[i]);
                B1[i] = fmaf(te, wk, B1[i]);
                C1[i] = fmaf(ee, wk, C1[i]);
                tt = fmaf(t2, w0 + wk, tt);
            }
        }
        __syncthreads();
        if (s + 1 < nslab) {
            tY4[i0] = ry0; if (w1) tY4[i1] = ry1;
            tH4[i0] = rh0; if (w1) tH4[i1] = rh1;
        }
        __syncthreads();
    }

    // ---- per-wg partials: contiguous block, coalesced stores ----
    float* pp = parts + (size_t)wg * PSTR;
    #pragma unroll
    for (int i = 0; i < 2; i++) {
        if (!val[i]) continue;
        const int p = pr[i];
        pp[p]            = D0[i];
        pp[NPAIR + p]    = B0[i];
        pp[2*NPAIR + p]  = C0[i];
        pp[3*NPAIR + p]  = D1[i];   // zero when cv<10
        pp[4*NPAIR + p]  = B1[i];
        pp[5*NPAIR + p]  = C1[i];
    }

    // ---- scalar sums: shuffle -> LDS -> 4 floats per wg ----
    const int lane = tid & 63, wv = tid >> 6;
    #pragma unroll
    for (int off = 32; off > 0; off >>= 1) {
        obj   += __shfl_down(obj,   off);
        noobj += __shfl_down(noobj, off);
        coord += __shfl_down(coord, off);
        tt    += __shfl_down(tt,    off);
    }
    if (lane == 0) { scr[0][wv] = obj; scr[1][wv] = noobj; scr[2][wv] = coord; scr[3][wv] = tt; }
    __syncthreads();
    if (tid < 4) {
        float sacc = 0.f;
        #pragma unroll
        for (int w = 0; w < THREADS / 64; w++) sacc += scr[tid][w];
        scal[wg * 4 + tid] = sacc;
    }
}

// 29 blocks x 512: block owns 64 float4-columns; 8 subgroups each fold nwg/8 wgs
// with coalesced float4 loads; LDS fold; plain store straight into tbl.
__global__ __launch_bounds__(512)
void yolo_reduce(const float* __restrict__ parts, float* __restrict__ tbl, int nwg)
{
    const int lane = threadIdx.x & 63;          // float4 column lane
    const int sub  = threadIdx.x >> 6;          // 0..7
    const int f4i  = blockIdx.x * 64 + lane;
    const int wps  = nwg >> 3;                  // wgs per subgroup (32 for nwg=256)

    float4 s = make_float4(0.f, 0.f, 0.f, 0.f);
    if (f4i < F4TOT) {
        const float* q = parts + (size_t)(sub * wps) * PSTR + f4i * 4;
        for (int w = 0; w < wps; ++w) {
            float4 a = *(const float4*)q;
            s.x += a.x; s.y += a.y; s.z += a.z; s.w += a.w;
            q += PSTR;
        }
    }
    __shared__ float4 sred[8][64];
    sred[sub][lane] = s;
    __syncthreads();
    if (threadIdx.x < 64 && f4i < F4TOT) {
        float4 t = sred[0][lane];
        #pragma unroll
        for (int c = 1; c < 8; c++) {
            float4 a = sred[c][lane];
            t.x += a.x; t.y += a.y; t.z += a.z; t.w += a.w;
        }
        *(float4*)(tbl + f4i * 4) = t;
    }
}

__global__ __launch_bounds__(1024)
void yolo_final(const float* __restrict__ tbl, const float* __restrict__ scal,
                float* __restrict__ out, int nwg)
{
    float v = 0.f;

    for (int s = threadIdx.x; s < NPAIR; s += 1024) {
        const int cidx = s % 25;
        float D0 = tbl[s], B0 = tbl[NPAIR + s], C0 = tbl[2*NPAIR + s];
        if (D0 > 0.f) v += C0 / (D0 * D0) - 2.f * B0 / D0;
        if (cidx >= 5) {
            float D1 = tbl[3*NPAIR + s], B1 = tbl[4*NPAIR + s], C1 = tbl[5*NPAIR + s];
            if (D1 > 0.f) v += C1 / (D1 * D1) - 2.f * B1 / D1;
        }
    }
    const float4* s4 = (const float4*)scal;
    for (int w = threadIdx.x; w < nwg; w += 1024) {
        float4 a = s4[w];
        v += a.x + 0.5f * a.y + 5.0f * a.z + a.w;
    }

    __shared__ float sred[16];
    #pragma unroll
    for (int off = 32; off > 0; off >>= 1) v += __shfl_down(v, off);
    const int lane = threadIdx.x & 63, wv = threadIdx.x >> 6;
    if (lane == 0) sred[wv] = v;
    __syncthreads();
    if (threadIdx.x == 0) {
        float tot = 0.f;
        #pragma unroll
        for (int w = 0; w < 16; w++) tot += sred[w];
        out[0] = tot / (float)NBATCH;
    }
}

extern "C" void kernel_launch(void* const* d_in, const int* in_sizes, int n_in,
                              void* d_out, int out_size, void* d_ws, size_t ws_size,
                              hipStream_t stream)
{
    const float* y  = (const float*)d_in[0];
    const float* yh = (const float*)d_in[1];
    float* out   = (float*)d_out;
    float* scal  = (float*)d_ws;
    float* tbl   = (float*)((char*)d_ws + 8192);
    float* parts = (float*)((char*)d_ws + 40960);

    const size_t per_wg = (size_t)PSTR * sizeof(float);   // 29.4 KB
    int nwg;
    if      (ws_size >= 40960 + 256 * per_wg) nwg = 256;
    else if (ws_size >= 40960 + 128 * per_wg) nwg = 128;
    else                                      nwg = 64;

    yolo_main<<<nwg, THREADS, 0, stream>>>(y, yh, scal, parts, nwg);
    yolo_reduce<<<(F4TOT + 63) / 64, 512, 0, stream>>>(parts, tbl, nwg);
    yolo_final<<<1, 1024, 0, stream>>>(tbl, scal, out, nwg);
}

// Round 11
// 30.366 us; speedup vs baseline: 1.0859x; 1.0859x over previous
//
#include <hip/hip_runtime.h>
#include <math.h>

#define CC 30
#define NBATCH 4096
#define NIJ 49
#define NPAIR 1225            // 49 ij * 25 tail channels (c = 5..29)
#define PSTR 7352             // per-chunk partial stride in floats (6*NPAIR, padded /4)
#define F4TOT (PSTR / 4)      // 1838

// ws layout (NO initialization required — every read location is written first):
//   offset 0      : sc[5*nchunk]       (written by yolo_main; weighted scalars)
//   offset 8192   : parts2[8][PSTR]    (written by yolo_reduce)
//   offset 243456 : parts[nchunk][PSTR](written by yolo_main)

// grid (5, nchunk) x 256. Thread = (ij, tail-channel) slot; streams its batch
// chunk directly from global (no LDS, no barriers in the hot loop).
__global__ __launch_bounds__(256)
void yolo_main(const float* __restrict__ y, const float* __restrict__ yh,
               float* __restrict__ sc, float* __restrict__ parts, int nchunk)
{
    const int tid   = threadIdx.x;
    const int x     = blockIdx.x;        // 0..4 slot slice
    const int chunk = blockIdx.y;
    const int bpc   = NBATCH / nchunk;   // 16 for nchunk=256
    const int b0    = chunk * bpc;

    const int  p  = x * 256 + tid;
    const bool pv = (p < NPAIR);
    const int  ps = pv ? p : 0;
    const int  ij = ps / 25;
    const int  c  = 5 + ps % 25;
    const bool ctail = (c >= 10);

    float D0=0.f,B0=0.f,C0=0.f,D1=0.f,B1=0.f,C1=0.f,tt=0.f;

    // ---- slot phase: stream batches, 4 loads/iter, zero LDS ----
    const float* qy = y  + ((size_t)b0 * NIJ + ij) * CC;
    const float* qh = yh + ((size_t)b0 * NIJ + ij) * CC;
    #pragma unroll 4
    for (int b = 0; b < bpc; b++) {
        const float y0 = qy[0], y5 = qy[5];
        const float t  = qy[c], th = qh[c];
        const float w0 = (pv && y0 == 1.0f) ? 1.f : 0.f;
        const float wk = (pv && ctail && y5 == 1.0f) ? 1.f : 0.f;
        const float e  = __expf(th);
        const float te = t * e, ee = e * e;
        D0 = fmaf(e,  w0, D0);
        B0 = fmaf(te, w0, B0);
        C0 = fmaf(ee, w0, C0);
        D1 = fmaf(e,  wk, D1);
        B1 = fmaf(te, wk, B1);
        C1 = fmaf(ee, wk, C1);
        tt = fmaf(t * t, w0 + wk, tt);
        qy += NIJ * CC; qh += NIJ * CC;
    }

    // ---- slot partials: coalesced scalar stores into this chunk's row ----
    if (pv) {
        float* pr = parts + (size_t)chunk * PSTR;
        pr[p]           = D0;
        pr[NPAIR + p]   = B0;
        pr[2*NPAIR + p] = C0;
        pr[3*NPAIR + p] = D1;
        pr[4*NPAIR + p] = B1;
        pr[5*NPAIR + p] = C1;
    }

    // ---- pointwise pass: cells of this block's ij-slice, once per cell ----
    const int ijs = (x * 256 + 24) / 25;                  // ceil(x*256/25)
    int ije = ((x + 1) * 256 + 24) / 25; if (ije > NIJ) ije = NIJ;
    const int nown = ije - ijs;                           // 11,10,10,10,8
    float obj = 0.f, noobj = 0.f, coord = 0.f;
    for (int t = tid; t < nown * bpc; t += 256) {
        const int bl = t / nown, il = t - bl * nown;
        const float* cy = y  + ((size_t)(b0 + bl) * NIJ + ijs + il) * CC;
        const float* ch = yh + ((size_t)(b0 + bl) * NIJ + ijs + il) * CC;
        float a0 = cy[0] - ch[0]; a0 *= a0;
        float a5 = cy[5] - ch[5]; a5 *= a5;
        const bool m0 = (cy[0] == 1.0f), m1 = (cy[5] == 1.0f);
        obj   += (m0 ? a0 : 0.f) + (m1 ? a5 : 0.f);
        noobj += (m0 ? 0.f : a0) + (m1 ? 0.f : a5);
        if (m0) {
            float a  = cy[1] - ch[1], b2 = cy[2] - ch[2];
            float c1 = sqrtf(cy[3]) - sqrtf(ch[3]);
            float c2 = sqrtf(cy[4]) - sqrtf(ch[4]);
            coord += a * a + b2 * b2 + c1 * c1 + c2 * c2;
        }
        if (m1) {
            float a  = cy[6] - ch[6], b2 = cy[7] - ch[7];
            float c1 = sqrtf(cy[8]) - sqrtf(ch[8]);
            float c2 = sqrtf(cy[9]) - sqrtf(ch[9]);
            coord += a * a + b2 * b2 + c1 * c1 + c2 * c2;
        }
    }

    // ---- block-weighted scalar -> sc[block] ----
    float v = obj + 0.5f * noobj + 5.f * coord + tt;
    __shared__ float sred[4];
    #pragma unroll
    for (int off = 32; off > 0; off >>= 1) v += __shfl_down(v, off);
    const int lane = tid & 63, wv = tid >> 6;
    if (lane == 0) sred[wv] = v;
    __syncthreads();
    if (tid == 0) sc[x + 5 * chunk] = sred[0] + sred[1] + sred[2] + sred[3];
}

// grid (29, 8) x 512: block (bx, cy) sums 64 float4-columns over 1/8 of the
// chunks (8-way sub-split inside the block), float4 loads, LDS fold, store.
__global__ __launch_bounds__(512)
void yolo_reduce(const float* __restrict__ parts, float* __restrict__ parts2, int nchunk)
{
    const int lane = threadIdx.x & 63;          // float4 column lane
    const int sub  = threadIdx.x >> 6;          // 0..7
    const int f4i  = blockIdx.x * 64 + lane;
    const int cy   = blockIdx.y;                // 0..7
    const int wpc  = nchunk >> 3;               // chunks per cy
    const int wps  = wpc >> 3;                  // chunks per subgroup

    float4 s = make_float4(0.f, 0.f, 0.f, 0.f);
    if (f4i < F4TOT) {
        const float* q = parts + (size_t)(cy * wpc + sub * wps) * PSTR + f4i * 4;
        for (int w = 0; w < wps; ++w) {
            float4 a = *(const float4*)q;
            s.x += a.x; s.y += a.y; s.z += a.z; s.w += a.w;
            q += PSTR;
        }
    }
    __shared__ float4 sred[8][64];
    sred[sub][lane] = s;
    __syncthreads();
    if (threadIdx.x < 64 && f4i < F4TOT) {
        float4 t = sred[0][lane];
        #pragma unroll
        for (int cc = 1; cc < 8; cc++) {
            float4 a = sred[cc][lane];
            t.x += a.x; t.y += a.y; t.z += a.z; t.w += a.w;
        }
        *(float4*)(parts2 + (size_t)cy * PSTR + f4i * 4) = t;
    }
}

__global__ __launch_bounds__(1024)
void yolo_final(const float* __restrict__ parts2, const float* __restrict__ sc,
                float* __restrict__ out, int nchunk)
{
    float v = 0.f;

    for (int s = threadIdx.x; s < NPAIR; s += 1024) {
        const int cidx = s % 25;
        float D0 = 0, B0 = 0, C0 = 0, D1 = 0, B1 = 0, C1 = 0;
        #pragma unroll
        for (int cc = 0; cc < 8; cc++) {
            const float* t = parts2 + (size_t)cc * PSTR;
            D0 += t[s];           B0 += t[NPAIR + s];   C0 += t[2*NPAIR + s];
            D1 += t[3*NPAIR + s]; B1 += t[4*NPAIR + s]; C1 += t[5*NPAIR + s];
        }
        if (D0 > 0.f) v += C0 / (D0 * D0) - 2.f * B0 / D0;
        if (cidx >= 5 && D1 > 0.f) v += C1 / (D1 * D1) - 2.f * B1 / D1;
    }
    for (int w = threadIdx.x; w < 5 * nchunk; w += 1024) v += sc[w];

    __shared__ float sred[16];
    #pragma unroll
    for (int off = 32; off > 0; off >>= 1) v += __shfl_down(v, off);
    const int lane = threadIdx.x & 63, wv = threadIdx.x >> 6;
    if (lane == 0) sred[wv] = v;
    __syncthreads();
    if (threadIdx.x == 0) {
        float tot = 0.f;
        #pragma unroll
        for (int w = 0; w < 16; w++) tot += sred[w];
        out[0] = tot / (float)NBATCH;
    }
}

extern "C" void kernel_launch(void* const* d_in, const int* in_sizes, int n_in,
                              void* d_out, int out_size, void* d_ws, size_t ws_size,
                              hipStream_t stream)
{
    const float* y  = (const float*)d_in[0];
    const float* yh = (const float*)d_in[1];
    float* out    = (float*)d_out;
    float* sc     = (float*)d_ws;
    float* parts2 = (float*)((char*)d_ws + 8192);
    float* parts  = (float*)((char*)d_ws + 243456);

    const size_t per_ch = (size_t)PSTR * sizeof(float);   // 29.4 KB
    int nchunk;
    if      (ws_size >= 243456 + 256 * per_ch) nchunk = 256;
    else if (ws_size >= 243456 + 128 * per_ch) nchunk = 128;
    else                                       nchunk = 64;

    dim3 gmain(5, nchunk);
    yolo_main<<<gmain, 256, 0, stream>>>(y, yh, sc, parts, nchunk);
    dim3 g2((F4TOT + 63) / 64, 8);
    yolo_reduce<<<g2, 512, 0, stream>>>(parts, parts2, nchunk);
    yolo_final<<<1, 1024, 0, stream>>>(parts2, sc, out, nchunk);
}

// Round 13
// 29.130 us; speedup vs baseline: 1.1320x; 1.0425x over previous
//
#include <hip/hip_runtime.h>
#include <math.h>

#define CC 30
#define NBATCH 4096
#define NIJ 49
#define NPAIR 1225            // 49 ij * 25 tail channels (c = 5..29)
#define PSTR 7352             // per-wg partial stride in floats (6*NPAIR=7350, padded to /4)
#define F4TOT (PSTR / 4)
#define THREADS 512
#define SLABF4 1470           // float4 count of a 4-batch slab of one tensor

// ws layout (NO initialization required — every read location is written first):
//   offset 0      : scal[nwg][4]        (written by yolo_main)
//   offset 8192   : parts2[8][PSTR]     (written by yolo_reduce)
//   offset 243456 : parts[nwg][PSTR]    (written by yolo_main)

__global__ __launch_bounds__(THREADS)
void yolo_main(const float* __restrict__ y, const float* __restrict__ yh,
               float* __restrict__ scal, float* __restrict__ parts, int nwg)
{
    __shared__ __align__(16) float tY[4 * 1470];   // 23.5 KB
    __shared__ __align__(16) float tH[4 * 1470];   // 23.5 KB
    __shared__ float scr[4][8];

    const int tid = threadIdx.x;
    const int wg  = blockIdx.x;
    const int bpw = NBATCH / nwg;        // 8 for nwg=512
    const int nslab = bpw >> 2;          // 2

    const int i0 = tid, i1 = tid + 512;
    const int i2r = tid + 1024;
    const int i2  = (i2r < SLABF4) ? i2r : (SLABF4 - 1);
    const bool w2 = (i2r < SLABF4);

    int  ijv[3], cv[3], pr[3];
    bool val[3];
    #pragma unroll
    for (int i = 0; i < 3; i++) {
        int p = tid + i * THREADS;
        val[i] = (p < NPAIR);
        pr[i]  = p;
        int pp = val[i] ? p : 0;
        ijv[i] = pp / 25;
        cv[i]  = 5 + pp % 25;
    }

    float D0[3] = {0,0,0}, B0[3] = {0,0,0}, C0[3] = {0,0,0};
    float D1[3] = {0,0,0}, B1[3] = {0,0,0}, C1[3] = {0,0,0};
    float obj = 0.f, noobj = 0.f, coord = 0.f, tt = 0.f;

    const float4* Yg = (const float4*)y;
    const float4* Hg = (const float4*)yh;
    float4* tY4 = (float4*)tY;
    float4* tH4 = (float4*)tH;

    // prologue: stage slab 0
    {
        const size_t f4 = (size_t)((wg * bpw) >> 2) * SLABF4;
        float4 a0 = Yg[f4+i0], a1 = Yg[f4+i1], a2 = Yg[f4+i2];
        float4 b0 = Hg[f4+i0], b1 = Hg[f4+i1], b2 = Hg[f4+i2];
        tY4[i0] = a0; tY4[i1] = a1; if (w2) tY4[i2] = a2;
        tH4[i0] = b0; tH4[i1] = b1; if (w2) tH4[i2] = b2;
    }
    __syncthreads();

    float4 ry0, ry1, ry2, rh0, rh1, rh2;

    for (int s = 0; s < nslab; s++) {
        if (s + 1 < nslab) {     // register prefetch of next slab (T14)
            const size_t nf4 = (size_t)((wg * bpw + (s+1)*4) >> 2) * SLABF4;
            ry0 = Yg[nf4+i0]; ry1 = Yg[nf4+i1]; ry2 = Yg[nf4+i2];
            rh0 = Hg[nf4+i0]; rh1 = Hg[nf4+i1]; rh2 = Hg[nf4+i2];
        }

        // ---- pointwise: 196 cells in this slab ----
        if (tid < 4 * NIJ) {
            const int base = tid * CC;
            float y0 = tY[base],     h0 = tH[base];
            float y5 = tY[base + 5], h5 = tH[base + 5];
            float d0 = y0 - h0; d0 *= d0;
            float d5 = y5 - h5; d5 *= d5;
            const bool m0 = (y0 == 1.0f), m1 = (y5 == 1.0f);
            obj   += (m0 ? d0 : 0.f) + (m1 ? d5 : 0.f);
            noobj += (m0 ? 0.f : d0) + (m1 ? 0.f : d5);
            if (m0) {
                float a  = tY[base + 1] - tH[base + 1];
                float b2 = tY[base + 2] - tH[base + 2];
                float c1 = sqrtf(tY[base + 3]) - sqrtf(tH[base + 3]);
                float c2 = sqrtf(tY[base + 4]) - sqrtf(tH[base + 4]);
                coord += a * a + b2 * b2 + c1 * c1 + c2 * c2;
            }
            if (m1) {
                float a  = tY[base + 6] - tH[base + 6];
                float b2 = tY[base + 7] - tH[base + 7];
                float c1 = sqrtf(tY[base + 8]) - sqrtf(tH[base + 8]);
                float c2 = sqrtf(tY[base + 9]) - sqrtf(tH[base + 9]);
                coord += a * a + b2 * b2 + c1 * c1 + c2 * c2;
            }
        }

        // ---- slot phase: register accumulation, no atomics ----
        #pragma unroll
        for (int b = 0; b < 4; b++) {
            #pragma unroll
            for (int i = 0; i < 3; i++) {
                if (!val[i]) continue;
                const int cb = b * 1470 + ijv[i] * CC;
                const float w0 = (tY[cb] == 1.0f) ? 1.f : 0.f;
                const float wk = (cv[i] >= 10 && tY[cb + 5] == 1.0f) ? 1.f : 0.f;
                const float t  = tY[cb + cv[i]];
                const float th = tH[cb + cv[i]];
                const float e  = __expf(th);
                const float te = t * e, ee = e * e, t2 = t * t;
                D0[i] = fmaf(e,  w0, D0[i]);
                B0[i] = fmaf(te, w0, B0[i]);
                C0[i] = fmaf(ee, w0, C0[i]);
                D1[i] = fmaf(e,  wk, D1[i]);
                B1[i] = fmaf(te, wk, B1[i]);
                C1[i] = fmaf(ee, wk, C1[i]);
                tt = fmaf(t2, w0 + wk, tt);
            }
        }
        __syncthreads();
        if (s + 1 < nslab) {
            tY4[i0] = ry0; tY4[i1] = ry1; if (w2) tY4[i2] = ry2;
            tH4[i0] = rh0; tH4[i1] = rh1; if (w2) tH4[i2] = rh2;
        }
        __syncthreads();
    }

    // ---- per-wg partials: contiguous block, coalesced stores ----
    float* pp = parts + (size_t)wg * PSTR;
    #pragma unroll
    for (int i = 0; i < 3; i++) {
        if (!val[i]) continue;
        const int p = pr[i];
        pp[p]            = D0[i];
        pp[NPAIR + p]    = B0[i];
        pp[2*NPAIR + p]  = C0[i];
        pp[3*NPAIR + p]  = D1[i];   // zero when cv<10
        pp[4*NPAIR + p]  = B1[i];
        pp[5*NPAIR + p]  = C1[i];
    }

    // ---- scalar sums: shuffle -> LDS -> 4 floats per wg ----
    const int lane = tid & 63, wv = tid >> 6;
    #pragma unroll
    for (int off = 32; off > 0; off >>= 1) {
        obj   += __shfl_down(obj,   off);
        noobj += __shfl_down(noobj, off);
        coord += __shfl_down(coord, off);
        tt    += __shfl_down(tt,    off);
    }
    if (lane == 0) { scr[0][wv] = obj; scr[1][wv] = noobj; scr[2][wv] = coord; scr[3][wv] = tt; }
    __syncthreads();
    if (tid < 4) {
        float sacc = 0.f;
        #pragma unroll
        for (int w = 0; w < THREADS / 64; w++) sacc += scr[tid][w];
        scal[wg * 4 + tid] = sacc;
    }
}

// grid (29, 8) x 512: block (bx, cy) sums 64 float4-columns over 1/8 of the wgs
// (8-way sub-split inside the block), float4 loads, LDS fold, plain store.
__global__ __launch_bounds__(512)
void yolo_reduce(const float* __restrict__ parts, float* __restrict__ parts2, int nwg)
{
    const int lane = threadIdx.x & 63;          // float4 column lane
    const int sub  = threadIdx.x >> 6;          // 0..7
    const int f4i  = blockIdx.x * 64 + lane;
    const int cy   = blockIdx.y;                // 0..7
    const int wpc  = nwg >> 3;                  // wgs per chunk (64 for nwg=512)
    const int wps  = wpc >> 3;                  // wgs per sub-group (8)

    float4 s = make_float4(0.f, 0.f, 0.f, 0.f);
    if (f4i < F4TOT) {
        const float* q = parts + (size_t)(cy * wpc + sub * wps) * PSTR + f4i * 4;
        for (int w = 0; w < wps; ++w) {
            float4 a = *(const float4*)q;
            s.x += a.x; s.y += a.y; s.z += a.z; s.w += a.w;
            q += PSTR;
        }
    }
    __shared__ float4 sred[8][64];
    sred[sub][lane] = s;
    __syncthreads();
    if (threadIdx.x < 64 && f4i < F4TOT) {
        float4 t = sred[0][lane];
        #pragma unroll
        for (int c = 1; c < 8; c++) {
            float4 a = sred[c][lane];
            t.x += a.x; t.y += a.y; t.z += a.z; t.w += a.w;
        }
        *(float4*)(parts2 + (size_t)cy * PSTR + f4i * 4) = t;
    }
}

__global__ __launch_bounds__(1024)
void yolo_final(const float* __restrict__ parts2, const float* __restrict__ scal,
                float* __restrict__ out, int nwg)
{
    float v = 0.f;

    for (int s = threadIdx.x; s < NPAIR; s += 1024) {
        const int cidx = s % 25;
        float D0 = 0, B0 = 0, C0 = 0, D1 = 0, B1 = 0, C1 = 0;
        #pragma unroll
        for (int c = 0; c < 8; c++) {
            const float* t = parts2 + (size_t)c * PSTR;
            D0 += t[s];           B0 += t[NPAIR + s];   C0 += t[2*NPAIR + s];
            D1 += t[3*NPAIR + s]; B1 += t[4*NPAIR + s]; C1 += t[5*NPAIR + s];
        }
        if (D0 > 0.f) v += C0 / (D0 * D0) - 2.f * B0 / D0;
        if (cidx >= 5 && D1 > 0.f) v += C1 / (D1 * D1) - 2.f * B1 / D1;
    }

    const float4* s4 = (const float4*)scal;
    for (int w = threadIdx.x; w < nwg; w += 1024) {
        float4 a = s4[w];
        v += a.x + 0.5f * a.y + 5.0f * a.z + a.w;
    }

    __shared__ float sred[16];
    #pragma unroll
    for (int off = 32; off > 0; off >>= 1) v += __shfl_down(v, off);
    const int lane = threadIdx.x & 63, wv = threadIdx.x >> 6;
    if (lane == 0) sred[wv] = v;
    __syncthreads();
    if (threadIdx.x == 0) {
        float tot = 0.f;
        #pragma unroll
        for (int w = 0; w < 16; w++) tot += sred[w];
        out[0] = tot / (float)NBATCH;
    }
}

extern "C" void kernel_launch(void* const* d_in, const int* in_sizes, int n_in,
                              void* d_out, int out_size, void* d_ws, size_t ws_size,
                              hipStream_t stream)
{
    const float* y  = (const float*)d_in[0];
    const float* yh = (const float*)d_in[1];
    float* out    = (float*)d_out;
    float* scal   = (float*)d_ws;
    float* parts2 = (float*)((char*)d_ws + 8192);
    float* parts  = (float*)((char*)d_ws + 243456);

    const size_t per_wg = (size_t)PSTR * sizeof(float);   // 29.4 KB
    int nwg;
    if      (ws_size >= 243456 + 512 * per_wg) nwg = 512;
    else if (ws_size >= 243456 + 256 * per_wg) nwg = 256;
    else                                       nwg = 128;

    yolo_main<<<nwg, THREADS, 0, stream>>>(y, yh, scal, parts, nwg);
    dim3 g2((F4TOT + 63) / 64, 8);
    yolo_reduce<<<g2, 512, 0, stream>>>(parts, parts2, nwg);
    yolo_final<<<1, 1024, 0, stream>>>(parts2, scal, out, nwg);
}

// Round 15
// 27.442 us; speedup vs baseline: 1.2016x; 1.0615x over previous
//
#include <hip/hip_runtime.h>
#include <math.h>

#define CC 30
#define NBATCH 4096
#define NIJ 49
#define NPAIR 1225            // 49 ij * 25 tail channels (c = 5..29)
#define PSTR 7352             // per-wg partial stride in floats (6*NPAIR=7350, padded to /4)
#define F4TOT (PSTR / 4)
#define THREADS 512
#define SLABF4 1470           // float4 count of a 4-batch slab of one tensor
#define SLABF  5880           // floats per 4-batch slab

// ws layout (NO initialization required — every read location is written first):
//   offset 0      : scal[nwg][4]        (written by yolo_main)
//   offset 8192   : parts2[8][PSTR]     (written by yolo_reduce)
//   offset 243456 : parts[nwg][PSTR]    (written by yolo_main)

__global__ __launch_bounds__(THREADS)
void yolo_main(const float* __restrict__ y, const float* __restrict__ yh,
               float* __restrict__ scal, float* __restrict__ parts, int nwg)
{
    __shared__ __align__(16) float tY[2][SLABF];   // 2 x 23.5 KB
    __shared__ __align__(16) float tH[2][SLABF];   // 2 x 23.5 KB
    __shared__ float scr[4][8];

    const int tid = threadIdx.x;
    const int wg  = blockIdx.x;
    const int bpw = NBATCH / nwg;        // 16 for nwg=256
    const int nslab = bpw >> 2;          // 4

    const int i0 = tid, i1 = tid + 512;
    const int i2r = tid + 1024;
    const int i2  = (i2r < SLABF4) ? i2r : (SLABF4 - 1);
    const bool w2 = (i2r < SLABF4);

    int  ijv[3], cv[3], pr[3];
    bool val[3];
    #pragma unroll
    for (int i = 0; i < 3; i++) {
        int p = tid + i * THREADS;
        val[i] = (p < NPAIR);
        pr[i]  = p;
        int pp = val[i] ? p : 0;
        ijv[i] = pp / 25;
        cv[i]  = 5 + pp % 25;
    }

    float D0[3] = {0,0,0}, B0[3] = {0,0,0}, C0[3] = {0,0,0};
    float D1[3] = {0,0,0}, B1[3] = {0,0,0}, C1[3] = {0,0,0};
    float obj = 0.f, noobj = 0.f, coord = 0.f, tt = 0.f;

    const float4* Yg = (const float4*)y;
    const float4* Hg = (const float4*)yh;

    // prologue: stage slab 0 into buffer 0
    {
        const size_t f4 = (size_t)((wg * bpw) >> 2) * SLABF4;
        float4 a0 = Yg[f4+i0], a1 = Yg[f4+i1], a2 = Yg[f4+i2];
        float4 b0 = Hg[f4+i0], b1 = Hg[f4+i1], b2 = Hg[f4+i2];
        float4* dY = (float4*)tY[0];
        float4* dH = (float4*)tH[0];
        dY[i0] = a0; dY[i1] = a1; if (w2) dY[i2] = a2;
        dH[i0] = b0; dH[i1] = b1; if (w2) dH[i2] = b2;
    }
    __syncthreads();

    for (int s = 0; s < nslab; s++) {
        const float* cy = tY[s & 1];
        const float* ch = tH[s & 1];
        const bool pf = (s + 1 < nslab);
        float4 ry0, ry1, ry2, rh0, rh1, rh2;
        if (pf) {                 // issue next slab's loads; they fly during compute
            const size_t nf4 = (size_t)((wg * bpw + (s+1)*4) >> 2) * SLABF4;
            ry0 = Yg[nf4+i0]; ry1 = Yg[nf4+i1]; ry2 = Yg[nf4+i2];
            rh0 = Hg[nf4+i0]; rh1 = Hg[nf4+i1]; rh2 = Hg[nf4+i2];
        }

        // ---- pointwise: 196 cells in this slab ----
        if (tid < 4 * NIJ) {
            const int base = tid * CC;
            float y0 = cy[base],     h0 = ch[base];
            float y5 = cy[base + 5], h5 = ch[base + 5];
            float d0 = y0 - h0; d0 *= d0;
            float d5 = y5 - h5; d5 *= d5;
            const bool m0 = (y0 == 1.0f), m1 = (y5 == 1.0f);
            obj   += (m0 ? d0 : 0.f) + (m1 ? d5 : 0.f);
            noobj += (m0 ? 0.f : d0) + (m1 ? 0.f : d5);
            if (m0) {
                float a  = cy[base + 1] - ch[base + 1];
                float b2 = cy[base + 2] - ch[base + 2];
                float c1 = sqrtf(cy[base + 3]) - sqrtf(ch[base + 3]);
                float c2 = sqrtf(cy[base + 4]) - sqrtf(ch[base + 4]);
                coord += a * a + b2 * b2 + c1 * c1 + c2 * c2;
            }
            if (m1) {
                float a  = cy[base + 6] - ch[base + 6];
                float b2 = cy[base + 7] - ch[base + 7];
                float c1 = sqrtf(cy[base + 8]) - sqrtf(ch[base + 8]);
                float c2 = sqrtf(cy[base + 9]) - sqrtf(ch[base + 9]);
                coord += a * a + b2 * b2 + c1 * c1 + c2 * c2;
            }
        }

        // ---- slot phase: register accumulation, no atomics ----
        #pragma unroll
        for (int b = 0; b < 4; b++) {
            #pragma unroll
            for (int i = 0; i < 3; i++) {
                if (!val[i]) continue;
                const int cb = b * 1470 + ijv[i] * CC;
                const float w0 = (cy[cb] == 1.0f) ? 1.f : 0.f;
                const float wk = (cv[i] >= 10 && cy[cb + 5] == 1.0f) ? 1.f : 0.f;
                const float t  = cy[cb + cv[i]];
                const float th = ch[cb + cv[i]];
                const float e  = __expf(th);
                const float te = t * e, ee = e * e, t2 = t * t;
                D0[i] = fmaf(e,  w0, D0[i]);
                B0[i] = fmaf(te, w0, B0[i]);
                C0[i] = fmaf(ee, w0, C0[i]);
                D1[i] = fmaf(e,  wk, D1[i]);
                B1[i] = fmaf(te, wk, B1[i]);
                C1[i] = fmaf(ee, wk, C1[i]);
                tt = fmaf(t2, w0 + wk, tt);
            }
        }

        // ---- write prefetched slab into the OTHER buffer (its last reader
        //      finished before the previous barrier) — ONE barrier per slab ----
        if (pf) {
            float4* dY = (float4*)tY[(s + 1) & 1];
            float4* dH = (float4*)tH[(s + 1) & 1];
            dY[i0] = ry0; dY[i1] = ry1; if (w2) dY[i2] = ry2;
            dH[i0] = rh0; dH[i1] = rh1; if (w2) dH[i2] = rh2;
        }
        __syncthreads();
    }

    // ---- per-wg partials: contiguous block, coalesced stores ----
    float* pp = parts + (size_t)wg * PSTR;
    #pragma unroll
    for (int i = 0; i < 3; i++) {
        if (!val[i]) continue;
        const int p = pr[i];
        pp[p]            = D0[i];
        pp[NPAIR + p]    = B0[i];
        pp[2*NPAIR + p]  = C0[i];
        pp[3*NPAIR + p]  = D1[i];   // zero when cv<10
        pp[4*NPAIR + p]  = B1[i];
        pp[5*NPAIR + p]  = C1[i];
    }

    // ---- scalar sums: shuffle -> LDS -> 4 floats per wg ----
    const int lane = tid & 63, wv = tid >> 6;
    #pragma unroll
    for (int off = 32; off > 0; off >>= 1) {
        obj   += __shfl_down(obj,   off);
        noobj += __shfl_down(noobj, off);
        coord += __shfl_down(coord, off);
        tt    += __shfl_down(tt,    off);
    }
    if (lane == 0) { scr[0][wv] = obj; scr[1][wv] = noobj; scr[2][wv] = coord; scr[3][wv] = tt; }
    __syncthreads();
    if (tid < 4) {
        float sacc = 0.f;
        #pragma unroll
        for (int w = 0; w < THREADS / 64; w++) sacc += scr[tid][w];
        scal[wg * 4 + tid] = sacc;
    }
}

// grid (29, 8) x 512: block (bx, cy) sums 64 float4-columns over 1/8 of the wgs
// (8-way sub-split inside the block), float4 loads, LDS fold, plain store.
__global__ __launch_bounds__(512)
void yolo_reduce(const float* __restrict__ parts, float* __restrict__ parts2, int nwg)
{
    const int lane = threadIdx.x & 63;          // float4 column lane
    const int sub  = threadIdx.x >> 6;          // 0..7
    const int f4i  = blockIdx.x * 64 + lane;
    const int cy   = blockIdx.y;                // 0..7
    const int wpc  = nwg >> 3;                  // wgs per chunk (32 for nwg=256)
    const int wps  = wpc >> 3;                  // wgs per sub-group (4)

    float4 s = make_float4(0.f, 0.f, 0.f, 0.f);
    if (f4i < F4TOT) {
        const float* q = parts + (size_t)(cy * wpc + sub * wps) * PSTR + f4i * 4;
        for (int w = 0; w < wps; ++w) {
            float4 a = *(const float4*)q;
            s.x += a.x; s.y += a.y; s.z += a.z; s.w += a.w;
            q += PSTR;
        }
    }
    __shared__ float4 sred[8][64];
    sred[sub][lane] = s;
    __syncthreads();
    if (threadIdx.x < 64 && f4i < F4TOT) {
        float4 t = sred[0][lane];
        #pragma unroll
        for (int c = 1; c < 8; c++) {
            float4 a = sred[c][lane];
            t.x += a.x; t.y += a.y; t.z += a.z; t.w += a.w;
        }
        *(float4*)(parts2 + (size_t)cy * PSTR + f4i * 4) = t;
    }
}

__global__ __launch_bounds__(1024)
void yolo_final(const float* __restrict__ parts2, const float* __restrict__ scal,
                float* __restrict__ out, int nwg)
{
    float v = 0.f;

    for (int s = threadIdx.x; s < NPAIR; s += 1024) {
        const int cidx = s % 25;
        float D0 = 0, B0 = 0, C0 = 0, D1 = 0, B1 = 0, C1 = 0;
        #pragma unroll
        for (int c = 0; c < 8; c++) {
            const float* t = parts2 + (size_t)c * PSTR;
            D0 += t[s];           B0 += t[NPAIR + s];   C0 += t[2*NPAIR + s];
            D1 += t[3*NPAIR + s]; B1 += t[4*NPAIR + s]; C1 += t[5*NPAIR + s];
        }
        if (D0 > 0.f) v += C0 / (D0 * D0) - 2.f * B0 / D0;
        if (cidx >= 5 && D1 > 0.f) v += C1 / (D1 * D1) - 2.f * B1 / D1;
    }

    const float4* s4 = (const float4*)scal;
    for (int w = threadIdx.x; w < nwg; w += 1024) {
        float4 a = s4[w];
        v += a.x + 0.5f * a.y + 5.0f * a.z + a.w;
    }

    __shared__ float sred[16];
    #pragma unroll
    for (int off = 32; off > 0; off >>= 1) v += __shfl_down(v, off);
    const int lane = threadIdx.x & 63, wv = threadIdx.x >> 6;
    if (lane == 0) sred[wv] = v;
    __syncthreads();
    if (threadIdx.x == 0) {
        float tot = 0.f;
        #pragma unroll
        for (int w = 0; w < 16; w++) tot += sred[w];
        out[0] = tot / (float)NBATCH;
    }
}

extern "C" void kernel_launch(void* const* d_in, const int* in_sizes, int n_in,
                              void* d_out, int out_size, void* d_ws, size_t ws_size,
                              hipStream_t stream)
{
    const float* y  = (const float*)d_in[0];
    const float* yh = (const float*)d_in[1];
    float* out    = (float*)d_out;
    float* scal   = (float*)d_ws;
    float* parts2 = (float*)((char*)d_ws + 8192);
    float* parts  = (float*)((char*)d_ws + 243456);

    const size_t per_wg = (size_t)PSTR * sizeof(float);   // 29.4 KB
    int nwg;
    if      (ws_size >= 243456 + 256 * per_wg) nwg = 256;
    else if (ws_size >= 243456 + 128 * per_wg) nwg = 128;
    else                                       nwg = 64;

    yolo_main<<<nwg, THREADS, 0, stream>>>(y, yh, scal, parts, nwg);
    dim3 g2((F4TOT + 63) / 64, 8);
    yolo_reduce<<<g2, 512, 0, stream>>>(parts, parts2, nwg);
    yolo_final<<<1, 1024, 0, stream>>>(parts2, scal, out, nwg);
}